// Round 1
// baseline (4715.497 us; speedup 1.0000x reference)
//
#include <hip/hip_runtime.h>
#include <math.h>

#define B_N 4096
#define D_F 2048
#define K_P 512
#define NGMAX 4096
#define MU 0.9f
#define OMU (1.0f - MU)
#define FLTMAX 3.402823466e+38f
#define IMAX 0x7FFFFFFF

__device__ __forceinline__ bool argless(float v1, int i1, float v2, int i2) {
    return (v1 < v2) || (v1 == v2 && i1 < i2);
}

// -------- prep: compact gated indices, counts --------
__global__ void k_prep(const int* __restrict__ g, int* __restrict__ gsteps,
                       int* __restrict__ scal) {
    __shared__ int s[1024];
    __shared__ int base;
    int tid = threadIdx.x;
    if (tid == 0) base = 0;
    __syncthreads();
    for (int c = 0; c < 4; ++c) {
        int i = c * 1024 + tid;
        int gi = (g[i] != 0) ? 1 : 0;
        s[tid] = gi;
        __syncthreads();
        for (int off = 1; off < 1024; off <<= 1) {
            int v = (tid >= off) ? s[tid - off] : 0;
            __syncthreads();
            s[tid] += v;
            __syncthreads();
        }
        int pos = base + s[tid] - 1;
        if (gi) gsteps[pos] = i;
        __syncthreads();
        if (tid == 1023) base += s[1023];
        __syncthreads();
    }
    if (tid == 0) { scal[0] = base; scal[1] = B_N - base; }
}

// -------- row squared norms (wave per row) --------
__global__ void k_rownorm(const float* __restrict__ src, float* __restrict__ dst, int nrows) {
    int row = blockIdx.x * 4 + (threadIdx.x >> 6);
    int lane = threadIdx.x & 63;
    if (row >= nrows) return;
    const float* p = src + (size_t)row * D_F;
    float acc = 0.f;
    for (int d0 = lane * 4; d0 < D_F; d0 += 256) {
        float4 v = *(const float4*)(p + d0);
        acc += v.x * v.x + v.y * v.y + v.z * v.z + v.w * v.w;
    }
    for (int off = 32; off; off >>= 1) acc += __shfl_xor(acc, off);
    if (lane == 0) dst[row] = acc;
}

// -------- anomaly column sums (partials) --------
__global__ void k_colsum(const float* __restrict__ Z, const int* __restrict__ g,
                         float* __restrict__ anom_part) {
    int d = blockIdx.x * 256 + threadIdx.x;
    int rc = blockIdx.y;
    float acc = 0.f;
    int r0 = rc * 128;
    for (int r = r0; r < r0 + 128; ++r) {
        if (g[r] == 0) acc += Z[(size_t)r * D_F + d];
    }
    anom_part[(size_t)rc * D_F + d] = acc;
}

// -------- finalize m_a (reduce partials, divide, ||m_a||^2) --------
__global__ void k_fin_ma(const float* __restrict__ anom_part, const float* __restrict__ ma_in,
                         const int* __restrict__ scal, float* __restrict__ m_a_used,
                         float* __restrict__ scal_f) {
    __shared__ float red[1024];
    int tid = threadIdx.x;
    int na = scal[1];
    float m2 = 0.f;
    for (int dd = tid; dd < D_F; dd += 1024) {
        float s = 0.f;
        for (int c = 0; c < 32; ++c) s += anom_part[(size_t)c * D_F + dd];
        float v = (na > 0) ? (s / (float)na) : ma_in[dd];
        m_a_used[dd] = v;
        m2 += v * v;
    }
    red[tid] = m2;
    __syncthreads();
    for (int off = 512; off; off >>= 1) {
        if (tid < off) red[tid] += red[tid + off];
        __syncthreads();
    }
    if (tid == 0) scal_f[0] = red[0];
}

// -------- GEMM (NT: C = A * B^T), 64x64 tile, BK=16, 256 thr, 4x4 micro --------
// MODE 0: A rows = [Z[gsteps[0..ng)], P0[0..512)], B rows = Z[gsteps[0..ng)]
//         C: rows<ng -> Gram[m][n] (stride NGMAX); rows>=ng -> Dot[m-ng][n] (stride NGMAX)
// MODE 1: A = Z (B_N rows), B = Pn (K_P rows), C = Dotf[m][n] (stride K_P)
template <int MODE>
__global__ void k_gemm(const float* __restrict__ Z, const float* __restrict__ P0,
                       const float* __restrict__ Pn, const int* __restrict__ gsteps,
                       const int* __restrict__ scal, float* __restrict__ Gram,
                       float* __restrict__ Dot, float* __restrict__ Dotf) {
    int ng = scal[0];
    int M = (MODE == 0) ? (ng + K_P) : B_N;
    int N = (MODE == 0) ? ng : K_P;
    int mb = blockIdx.y * 64, nb = blockIdx.x * 64;
    if (mb >= M || nb >= N) return;

    __shared__ float As[16][68];
    __shared__ float Bs[16][68];
    __shared__ const float* rowA[64];
    __shared__ const float* rowB[64];

    int tid = threadIdx.x;
    if (tid < 64) {
        int gm = mb + tid;
        const float* pa = nullptr;
        if (MODE == 0) {
            if (gm < ng) pa = Z + (size_t)gsteps[gm] * D_F;
            else if (gm < ng + K_P) pa = P0 + (size_t)(gm - ng) * D_F;
        } else {
            if (gm < B_N) pa = Z + (size_t)gm * D_F;
        }
        rowA[tid] = pa;
    } else if (tid < 128) {
        int t = tid - 64;
        int gn = nb + t;
        const float* pb = nullptr;
        if (MODE == 0) { if (gn < ng) pb = Z + (size_t)gsteps[gn] * D_F; }
        else { if (gn < K_P) pb = Pn + (size_t)gn * D_F; }
        rowB[t] = pb;
    }
    __syncthreads();

    int r = tid & 63, kq = tid >> 6;       // staging: row r, k-quarter kq
    int tm = tid >> 4, tn = tid & 15;      // micro-tile coords
    const float* pa = rowA[r];
    const float* pb = rowB[r];

    float acc[4][4] = {};
    for (int k0 = 0; k0 < D_F; k0 += 16) {
        float4 av = pa ? *(const float4*)(pa + k0 + kq * 4) : make_float4(0.f, 0.f, 0.f, 0.f);
        float4 bv = pb ? *(const float4*)(pb + k0 + kq * 4) : make_float4(0.f, 0.f, 0.f, 0.f);
        __syncthreads();
        As[kq * 4 + 0][r] = av.x; As[kq * 4 + 1][r] = av.y;
        As[kq * 4 + 2][r] = av.z; As[kq * 4 + 3][r] = av.w;
        Bs[kq * 4 + 0][r] = bv.x; Bs[kq * 4 + 1][r] = bv.y;
        Bs[kq * 4 + 2][r] = bv.z; Bs[kq * 4 + 3][r] = bv.w;
        __syncthreads();
#pragma unroll
        for (int kk = 0; kk < 16; ++kk) {
            float4 a = *(const float4*)&As[kk][tm * 4];
            float4 b = *(const float4*)&Bs[kk][tn * 4];
            float aa[4] = {a.x, a.y, a.z, a.w};
            float bb[4] = {b.x, b.y, b.z, b.w};
#pragma unroll
            for (int i = 0; i < 4; ++i)
#pragma unroll
                for (int j = 0; j < 4; ++j) acc[i][j] += aa[i] * bb[j];
        }
    }

#pragma unroll
    for (int i = 0; i < 4; ++i) {
        int gm = mb + tm * 4 + i;
        if (gm >= M) continue;
        float* crow;
        if (MODE == 0)
            crow = (gm < ng) ? (Gram + (size_t)gm * NGMAX) : (Dot + (size_t)(gm - ng) * NGMAX);
        else
            crow = Dotf + (size_t)gm * K_P;
#pragma unroll
        for (int j = 0; j < 4; ++j) {
            int gn = nb + tn * 4 + j;
            if (gn < N) crow[gn] = acc[i][j];
        }
    }
}

// -------- sequential scan (1 workgroup, 512 threads = 1 thread / prototype) --------
__global__ void k_scan(const float* __restrict__ Gram, float* __restrict__ Dot,
                       const float* __restrict__ pn2_0, const float* __restrict__ zn2,
                       const int* __restrict__ gsteps, const int* __restrict__ scal,
                       int* __restrict__ upd, int* __restrict__ rankw, int* __restrict__ cnt_out) {
    __shared__ float pn2[K_P];
    __shared__ int cnt[K_P];
    __shared__ float swv[8];
    __shared__ int swi[8];
    __shared__ int skstar;
    int tid = threadIdx.x;
    int lane = tid & 63;
    int w = tid >> 6;
    pn2[tid] = pn2_0[tid];
    cnt[tid] = 0;
    int ng = scal[0];
    __syncthreads();

    for (int j = 0; j < ng; ++j) {
        float dc = Dot[(size_t)tid * NGMAX + j];
        float val = pn2[tid] - 2.f * dc;
        int idx = tid;
        for (int off = 32; off; off >>= 1) {
            float ov = __shfl_xor(val, off);
            int oi = __shfl_xor(idx, off);
            if (argless(ov, oi, val, idx)) { val = ov; idx = oi; }
        }
        if (lane == 0) { swv[w] = val; swi[w] = idx; }
        __syncthreads();
        if (w == 0) {
            float v = (lane < 8) ? swv[lane] : FLTMAX;
            int ii = (lane < 8) ? swi[lane] : IMAX;
            for (int off = 4; off; off >>= 1) {
                float ov = __shfl_xor(v, off);
                int oi = __shfl_xor(ii, off);
                if (argless(ov, oi, v, ii)) { v = ov; ii = oi; }
            }
            if (lane == 0) { skstar = ii; upd[j] = ii; }
        }
        __syncthreads();
        int ks = skstar;
        if (tid == ks) {
            float z2 = zn2[gsteps[j]];
            pn2[ks] = MU * MU * pn2[ks] + 2.f * MU * OMU * dc + OMU * OMU * z2;
            rankw[j] = cnt[ks];
            cnt[ks] = cnt[ks] + 1;
        }
        const float* gr = Gram + (size_t)j * NGMAX;
        float* dr = Dot + (size_t)ks * NGMAX;
        for (int t = j + 1 + tid; t < ng; t += 512) {
            dr[t] = MU * dr[t] + OMU * gr[t];
        }
        __syncthreads();
    }
    cnt_out[tid] = cnt[tid];
}

// -------- materialize final prototypes (block per prototype) --------
__global__ void k_mat(const float* __restrict__ Z, const float* __restrict__ P0,
                      const int* __restrict__ gsteps, const int* __restrict__ scal,
                      const int* __restrict__ upd, const int* __restrict__ rankw,
                      const int* __restrict__ cnt, float* __restrict__ Pn) {
    int k = blockIdx.x;
    int tid = threadIdx.x;  // 256 threads; 2 float4 each (covers 2048 floats)
    int ng = scal[0];
    int c = cnt[k];
    float bw = powf(MU, (float)c);
    const float4* p0r = (const float4*)(P0 + (size_t)k * D_F);
    float4 a0 = p0r[tid], a1 = p0r[tid + 256];
    a0.x *= bw; a0.y *= bw; a0.z *= bw; a0.w *= bw;
    a1.x *= bw; a1.y *= bw; a1.z *= bw; a1.w *= bw;
    for (int j = 0; j < ng; ++j) {
        if (upd[j] == k) {
            float wgt = OMU * powf(MU, (float)(c - 1 - rankw[j]));
            const float4* zr = (const float4*)(Z + (size_t)gsteps[j] * D_F);
            float4 z0 = zr[tid], z1 = zr[tid + 256];
            a0.x += wgt * z0.x; a0.y += wgt * z0.y; a0.z += wgt * z0.z; a0.w += wgt * z0.w;
            a1.x += wgt * z1.x; a1.y += wgt * z1.y; a1.z += wgt * z1.z; a1.w += wgt * z1.w;
        }
    }
    float4* pnr = (float4*)(Pn + (size_t)k * D_F);
    pnr[tid] = a0;
    pnr[tid + 256] = a1;
}

// -------- top-3 nearest + pull-loss row sums (wave per row) --------
__global__ void k_top3(const float* __restrict__ Dotf, const float* __restrict__ pn2f,
                       const float* __restrict__ Z, const float* __restrict__ Pn,
                       float* __restrict__ rowsum) {
    int row = blockIdx.x * 4 + (threadIdx.x >> 6);
    int lane = threadIdx.x & 63;
    float bv0 = FLTMAX, bv1 = FLTMAX, bv2 = FLTMAX;
    int bi0 = IMAX, bi1 = IMAX, bi2 = IMAX;
    for (int t = 0; t < 8; ++t) {
        int k = lane + 64 * t;
        float v = pn2f[k] - 2.f * Dotf[(size_t)row * K_P + k];
        if (argless(v, k, bv0, bi0)) {
            bv2 = bv1; bi2 = bi1; bv1 = bv0; bi1 = bi0; bv0 = v; bi0 = k;
        } else if (argless(v, k, bv1, bi1)) {
            bv2 = bv1; bi2 = bi1; bv1 = v; bi1 = k;
        } else if (argless(v, k, bv2, bi2)) {
            bv2 = v; bi2 = k;
        }
    }
    for (int off = 32; off; off >>= 1) {
        float a0 = bv0, a1 = bv1, a2 = bv2;
        int x0 = bi0, x1 = bi1, x2 = bi2;
        float b0 = __shfl_xor(bv0, off), b1 = __shfl_xor(bv1, off), b2 = __shfl_xor(bv2, off);
        int y0 = __shfl_xor(bi0, off), y1 = __shfl_xor(bi1, off), y2 = __shfl_xor(bi2, off);
        float nv[3]; int ni[3];
#pragma unroll
        for (int s = 0; s < 3; ++s) {
            bool ta = argless(a0, x0, b0, y0);
            nv[s] = ta ? a0 : b0;
            ni[s] = ta ? x0 : y0;
            if (ta) { a0 = a1; x0 = x1; a1 = a2; x1 = x2; a2 = FLTMAX; x2 = IMAX; }
            else    { b0 = b1; y0 = y1; b1 = b2; y1 = y2; b2 = FLTMAX; y2 = IMAX; }
        }
        bv0 = nv[0]; bv1 = nv[1]; bv2 = nv[2];
        bi0 = ni[0]; bi1 = ni[1]; bi2 = ni[2];
    }
    const float* pa = Pn + (size_t)bi0 * D_F;
    const float* pb = Pn + (size_t)bi1 * D_F;
    const float* pc = Pn + (size_t)bi2 * D_F;
    const float* zr = Z + (size_t)row * D_F;
    const float third = 1.f / 3.f;
    float acc = 0.f;
    for (int d0 = lane * 4; d0 < D_F; d0 += 256) {
        float4 z = *(const float4*)(zr + d0);
        float4 A = *(const float4*)(pa + d0);
        float4 Bv = *(const float4*)(pb + d0);
        float4 C = *(const float4*)(pc + d0);
        float m, df;
        m = (A.x + Bv.x + C.x) * third; df = z.x - m; acc += df * df;
        m = (A.y + Bv.y + C.y) * third; df = z.y - m; acc += df * df;
        m = (A.z + Bv.z + C.z) * third; df = z.z - m; acc += df * df;
        m = (A.w + Bv.w + C.w) * third; df = z.w - m; acc += df * df;
    }
    for (int off = 32; off; off >>= 1) acc += __shfl_xor(acc, off);
    if (lane == 0) rowsum[row] = acc;
}

// -------- push-loss row values (wave per row) --------
__global__ void k_push(const float* __restrict__ Z, const float* __restrict__ m_a_used,
                       const float* __restrict__ zn2, const float* __restrict__ scal_f,
                       float* __restrict__ rowpush) {
    int row = blockIdx.x * 4 + (threadIdx.x >> 6);
    int lane = threadIdx.x & 63;
    const float* zr = Z + (size_t)row * D_F;
    float acc = 0.f;
    for (int d0 = lane * 4; d0 < D_F; d0 += 256) {
        float4 z = *(const float4*)(zr + d0);
        float4 m = *(const float4*)(m_a_used + d0);
        acc += z.x * m.x + z.y * m.y + z.z * m.z + z.w * m.w;
    }
    for (int off = 32; off; off >>= 1) acc += __shfl_xor(acc, off);
    if (lane == 0) {
        float d2 = zn2[row] - 2.f * acc + scal_f[0];
        float dist = sqrtf(fmaxf(d2, 0.f));
        rowpush[row] = fmaxf(1.f - dist, 0.f);  // DELTA = 1
    }
}

// -------- final combine --------
__global__ void k_final(const float* __restrict__ rowsum, const float* __restrict__ rowpush,
                        const int* __restrict__ scal, float* __restrict__ out) {
    __shared__ float red[1024];
    int tid = threadIdx.x;
    float s = 0.f;
    for (int i = tid; i < B_N; i += 1024) s += rowsum[i];
    red[tid] = s;
    __syncthreads();
    for (int off = 512; off; off >>= 1) {
        if (tid < off) red[tid] += red[tid + off];
        __syncthreads();
    }
    float pull = red[0] / ((float)B_N * (float)D_F);
    __syncthreads();
    float p = 0.f;
    for (int i = tid; i < B_N; i += 1024) p += rowpush[i];
    red[tid] = p;
    __syncthreads();
    for (int off = 512; off; off >>= 1) {
        if (tid < off) red[tid] += red[tid + off];
        __syncthreads();
    }
    if (tid == 0) {
        float lpush = (scal[1] > 0) ? (red[0] / (float)B_N) : 0.f;
        out[0] = pull + 0.5f * lpush;  // ALPHA_P=1, ALPHA_R=0.5
    }
}

extern "C" void kernel_launch(void* const* d_in, const int* in_sizes, int n_in,
                              void* d_out, int out_size, void* d_ws, size_t ws_size,
                              hipStream_t stream) {
    const float* Z = (const float*)d_in[0];
    const int* g = (const int*)d_in[1];
    const float* P0 = (const float*)d_in[2];
    const float* ma_in = (const float*)d_in[4];  // d_in[3] proto_age: unused by the loss
    float* out = (float*)d_out;

    float* ws = (float*)d_ws;
    float* Gram = ws;                                   // 16M floats (64MB)
    float* Dotf = ws;                                   // overlaps Gram (Gram dead by then)
    float* Dot = ws + (size_t)NGMAX * NGMAX;            // 512*4096
    float* Pn = Dot + (size_t)K_P * NGMAX;              // 512*2048
    float* zn2 = Pn + (size_t)K_P * D_F;                // 4096
    float* pn2_0 = zn2 + B_N;                           // 512
    float* pn2f = pn2_0 + K_P;                          // 512
    float* anom_part = pn2f + K_P;                      // 32*2048
    float* m_a_used = anom_part + 32 * D_F;             // 2048
    float* rowsum = m_a_used + D_F;                     // 4096
    float* rowpush = rowsum + B_N;                      // 4096
    float* scal_f = rowpush + B_N;                      // 16
    int* gsteps = (int*)(scal_f + 16);                  // 4096
    int* upd = gsteps + B_N;                            // 4096
    int* rankw = upd + B_N;                             // 4096
    int* cnt = rankw + B_N;                             // 512
    int* scal = cnt + K_P;                              // 16

    k_prep<<<1, 1024, 0, stream>>>(g, gsteps, scal);
    k_rownorm<<<(B_N + 3) / 4, 256, 0, stream>>>(Z, zn2, B_N);
    k_rownorm<<<(K_P + 3) / 4, 256, 0, stream>>>(P0, pn2_0, K_P);
    k_colsum<<<dim3(D_F / 256, 32), 256, 0, stream>>>(Z, g, anom_part);
    k_fin_ma<<<1, 1024, 0, stream>>>(anom_part, ma_in, scal, m_a_used, scal_f);
    k_gemm<0><<<dim3(NGMAX / 64, (NGMAX + K_P) / 64), 256, 0, stream>>>(
        Z, P0, Pn, gsteps, scal, Gram, Dot, Dotf);
    k_scan<<<1, 512, 0, stream>>>(Gram, Dot, pn2_0, zn2, gsteps, scal, upd, rankw, cnt);
    k_mat<<<K_P, 256, 0, stream>>>(Z, P0, gsteps, scal, upd, rankw, cnt, Pn);
    k_rownorm<<<(K_P + 3) / 4, 256, 0, stream>>>(Pn, pn2f, K_P);
    k_gemm<1><<<dim3(K_P / 64, B_N / 64), 256, 0, stream>>>(
        Z, P0, Pn, gsteps, scal, Gram, Dot, Dotf);
    k_top3<<<B_N / 4, 256, 0, stream>>>(Dotf, pn2f, Z, Pn, rowsum);
    k_push<<<B_N / 4, 256, 0, stream>>>(Z, m_a_used, zn2, scal_f, rowpush);
    k_final<<<1, 1024, 0, stream>>>(rowsum, rowpush, scal, out);
}

// Round 2
// 4511.356 us; speedup vs baseline: 1.0453x; 1.0453x over previous
//
#include <hip/hip_runtime.h>
#include <math.h>

#define B_N 4096
#define D_F 2048
#define K_P 512
#define NGMAX 4096
#define MU 0.9f
#define OMU (1.0f - MU)
#define FLTMAX 3.402823466e+38f
#define IMAX 0x7FFFFFFF
#define TILE 64

// LDS carve sizes (floats/ints)
#define SMEM_FLOATS (512 * 65 + 64 * 65 + 64 + 64 + 64)
#define SMEM_INTS (512 + 512 + 64 + 64 + 64 + 64 + 65 + 1)
#define SMEM_BYTES ((SMEM_FLOATS + SMEM_INTS) * 4)

__device__ __forceinline__ bool argless(float v1, int i1, float v2, int i2) {
    return (v1 < v2) || (v1 == v2 && i1 < i2);
}

// -------- prep: compact gated indices, counts --------
__global__ void k_prep(const int* __restrict__ g, int* __restrict__ gsteps,
                       int* __restrict__ scal) {
    __shared__ int s[1024];
    __shared__ int base;
    int tid = threadIdx.x;
    if (tid == 0) base = 0;
    __syncthreads();
    for (int c = 0; c < 4; ++c) {
        int i = c * 1024 + tid;
        int gi = (g[i] != 0) ? 1 : 0;
        s[tid] = gi;
        __syncthreads();
        for (int off = 1; off < 1024; off <<= 1) {
            int v = (tid >= off) ? s[tid - off] : 0;
            __syncthreads();
            s[tid] += v;
            __syncthreads();
        }
        int pos = base + s[tid] - 1;
        if (gi) gsteps[pos] = i;
        __syncthreads();
        if (tid == 1023) base += s[1023];
        __syncthreads();
    }
    if (tid == 0) { scal[0] = base; scal[1] = B_N - base; }
}

// -------- row squared norms (wave per row) --------
__global__ void k_rownorm(const float* __restrict__ src, float* __restrict__ dst, int nrows) {
    int row = blockIdx.x * 4 + (threadIdx.x >> 6);
    int lane = threadIdx.x & 63;
    if (row >= nrows) return;
    const float* p = src + (size_t)row * D_F;
    float acc = 0.f;
    for (int d0 = lane * 4; d0 < D_F; d0 += 256) {
        float4 v = *(const float4*)(p + d0);
        acc += v.x * v.x + v.y * v.y + v.z * v.z + v.w * v.w;
    }
    for (int off = 32; off; off >>= 1) acc += __shfl_xor(acc, off);
    if (lane == 0) dst[row] = acc;
}

// -------- anomaly column sums (partials) --------
__global__ void k_colsum(const float* __restrict__ Z, const int* __restrict__ g,
                         float* __restrict__ anom_part) {
    int d = blockIdx.x * 256 + threadIdx.x;
    int rc = blockIdx.y;
    float acc = 0.f;
    int r0 = rc * 128;
    for (int r = r0; r < r0 + 128; ++r) {
        if (g[r] == 0) acc += Z[(size_t)r * D_F + d];
    }
    anom_part[(size_t)rc * D_F + d] = acc;
}

// -------- finalize m_a (reduce partials, divide, ||m_a||^2) --------
__global__ void k_fin_ma(const float* __restrict__ anom_part, const float* __restrict__ ma_in,
                         const int* __restrict__ scal, float* __restrict__ m_a_used,
                         float* __restrict__ scal_f) {
    __shared__ float red[1024];
    int tid = threadIdx.x;
    int na = scal[1];
    float m2 = 0.f;
    for (int dd = tid; dd < D_F; dd += 1024) {
        float s = 0.f;
        for (int c = 0; c < 32; ++c) s += anom_part[(size_t)c * D_F + dd];
        float v = (na > 0) ? (s / (float)na) : ma_in[dd];
        m_a_used[dd] = v;
        m2 += v * v;
    }
    red[tid] = m2;
    __syncthreads();
    for (int off = 512; off; off >>= 1) {
        if (tid < off) red[tid] += red[tid + off];
        __syncthreads();
    }
    if (tid == 0) scal_f[0] = red[0];
}

// -------- GEMM (NT: C = A * B^T), 64x64 tile, BK=16, 256 thr, 4x4 micro --------
template <int MODE>
__global__ void k_gemm(const float* __restrict__ Z, const float* __restrict__ P0,
                       const float* __restrict__ Pn, const int* __restrict__ gsteps,
                       const int* __restrict__ scal, float* __restrict__ Gram,
                       float* __restrict__ Dot, float* __restrict__ Dotf) {
    int ng = scal[0];
    int M = (MODE == 0) ? (ng + K_P) : B_N;
    int N = (MODE == 0) ? ng : K_P;
    int mb = blockIdx.y * 64, nb = blockIdx.x * 64;
    if (mb >= M || nb >= N) return;

    __shared__ float As[16][68];
    __shared__ float Bs[16][68];
    __shared__ const float* rowA[64];
    __shared__ const float* rowB[64];

    int tid = threadIdx.x;
    if (tid < 64) {
        int gm = mb + tid;
        const float* pa = nullptr;
        if (MODE == 0) {
            if (gm < ng) pa = Z + (size_t)gsteps[gm] * D_F;
            else if (gm < ng + K_P) pa = P0 + (size_t)(gm - ng) * D_F;
        } else {
            if (gm < B_N) pa = Z + (size_t)gm * D_F;
        }
        rowA[tid] = pa;
    } else if (tid < 128) {
        int t = tid - 64;
        int gn = nb + t;
        const float* pb = nullptr;
        if (MODE == 0) { if (gn < ng) pb = Z + (size_t)gsteps[gn] * D_F; }
        else { if (gn < K_P) pb = Pn + (size_t)gn * D_F; }
        rowB[t] = pb;
    }
    __syncthreads();

    int r = tid & 63, kq = tid >> 6;
    int tm = tid >> 4, tn = tid & 15;
    const float* pa = rowA[r];
    const float* pb = rowB[r];

    float acc[4][4] = {};
    for (int k0 = 0; k0 < D_F; k0 += 16) {
        float4 av = pa ? *(const float4*)(pa + k0 + kq * 4) : make_float4(0.f, 0.f, 0.f, 0.f);
        float4 bv = pb ? *(const float4*)(pb + k0 + kq * 4) : make_float4(0.f, 0.f, 0.f, 0.f);
        __syncthreads();
        As[kq * 4 + 0][r] = av.x; As[kq * 4 + 1][r] = av.y;
        As[kq * 4 + 2][r] = av.z; As[kq * 4 + 3][r] = av.w;
        Bs[kq * 4 + 0][r] = bv.x; Bs[kq * 4 + 1][r] = bv.y;
        Bs[kq * 4 + 2][r] = bv.z; Bs[kq * 4 + 3][r] = bv.w;
        __syncthreads();
#pragma unroll
        for (int kk = 0; kk < 16; ++kk) {
            float4 a = *(const float4*)&As[kk][tm * 4];
            float4 b = *(const float4*)&Bs[kk][tn * 4];
            float aa[4] = {a.x, a.y, a.z, a.w};
            float bb[4] = {b.x, b.y, b.z, b.w};
#pragma unroll
            for (int i = 0; i < 4; ++i)
#pragma unroll
                for (int j = 0; j < 4; ++j) acc[i][j] += aa[i] * bb[j];
        }
    }

#pragma unroll
    for (int i = 0; i < 4; ++i) {
        int gm = mb + tm * 4 + i;
        if (gm >= M) continue;
        float* crow;
        if (MODE == 0)
            crow = (gm < ng) ? (Gram + (size_t)gm * NGMAX) : (Dot + (size_t)(gm - ng) * NGMAX);
        else
            crow = Dotf + (size_t)gm * K_P;
#pragma unroll
        for (int j = 0; j < 4; ++j) {
            int gn = nb + tn * 4 + j;
            if (gn < N) crow[gn] = acc[i][j];
        }
    }
}

// -------- tiled sequential scan --------
// One workgroup, 512 threads (8 waves). Per 64-column tile:
//   L: load dot-tile + gram diag block into LDS (all waves)
//   S: wave 0 runs 64 sequential argmin/EMA steps entirely in LDS
//   U: all waves apply the tile's grouped row updates to remaining global Dot cols
__global__ __launch_bounds__(512, 1)
void k_scan_tiled(const float* __restrict__ Gram, float* __restrict__ Dot,
                  const float* __restrict__ pn2_0, const float* __restrict__ zn2,
                  const int* __restrict__ gsteps, const int* __restrict__ scal,
                  int* __restrict__ upd, int* __restrict__ rankw, int* __restrict__ cnt_out) {
    extern __shared__ char smem_raw[];
    float* sdot = (float*)smem_raw;             // [512][65]
    float* sgram = sdot + 512 * 65;             // [64][65]
    float* szn2 = sgram + 64 * 65;              // [64]
    float* stepw = szn2 + 64;                   // [64]
    float* srow_scale = stepw + 64;             // [64]
    int* scnt = (int*)(srow_scale + 64);        // [512] tile win counts
    int* srowidx = scnt + 512;                  // [512]
    int* stwin = srowidx + 512;                 // [64] winner row per tile step
    int* strank = stwin + 64;                   // [64] tile-rank of step within its row
    int* srows = strank + 64;                   // [64] distinct rows touched
    int* sorder = srows + 64;                   // [64] steps sorted by (row, rank)
    int* srowstart = sorder + 64;               // [65]
    int* snrows = srowstart + 65;               // [1]

    int tid = threadIdx.x;
    int lane = tid & 63;
    int wave = tid >> 6;
    int ng = scal[0];

    // wave-0 lane-private state: lane owns rows {r*64+lane}
    float pn2r[8];
    int cntg[8];
    if (wave == 0) {
#pragma unroll
        for (int r = 0; r < 8; ++r) { pn2r[r] = pn2_0[r * 64 + lane]; cntg[r] = 0; }
    }

    int ntiles = (ng + TILE - 1) / TILE;
    for (int T = 0; T < ntiles; ++T) {
        int j0 = T * TILE;
        int tlen = min(TILE, ng - j0);

        // ---- phase L ----
        {
            const float* src = Dot + (size_t)tid * NGMAX + j0;
            float* drow = sdot + tid * 65;
#pragma unroll
            for (int x = 0; x < 64; x += 4) {
                float4 v = *(const float4*)(src + x);
                drow[x] = v.x; drow[x + 1] = v.y; drow[x + 2] = v.z; drow[x + 3] = v.w;
            }
        }
        {
            int t = tid >> 3, xo = (tid & 7) * 8;
            const float* src = Gram + (size_t)(j0 + t) * NGMAX + j0 + xo;
            float4 a = *(const float4*)(src);
            float4 b = *(const float4*)(src + 4);
            float* dst = sgram + t * 65 + xo;
            dst[0] = a.x; dst[1] = a.y; dst[2] = a.z; dst[3] = a.w;
            dst[4] = b.x; dst[5] = b.y; dst[6] = b.z; dst[7] = b.w;
        }
        scnt[tid] = 0;
        if (tid == 0) *snrows = 0;
        if (tid < TILE) szn2[tid] = (tid < tlen) ? zn2[gsteps[j0 + tid]] : 0.f;
        __syncthreads();

        // ---- phase S (wave 0 only) ----
        if (wave == 0) {
            float d8[8], pv[8];
#pragma unroll
            for (int r = 0; r < 8; ++r) d8[r] = sdot[(r * 64 + lane) * 65];
            for (int jl = 0; jl < tlen; ++jl) {
                // local argmin over the lane's 8 rows (ascending row idx -> first-min tie-break)
                float bv = pn2r[0] - 2.f * d8[0];
                int bi = lane;
#pragma unroll
                for (int r = 1; r < 8; ++r) {
                    float v = pn2r[r] - 2.f * d8[r];
                    int ii = r * 64 + lane;
                    if (v < bv) { bv = v; bi = ii; }
                }
                // prefetch next column (off the critical path)
                bool havenext = (jl + 1 < tlen);
                if (havenext) {
#pragma unroll
                    for (int r = 0; r < 8; ++r) pv[r] = sdot[(r * 64 + lane) * 65 + jl + 1];
                }
                // 64-lane butterfly argmin
#pragma unroll
                for (int off = 32; off; off >>= 1) {
                    float ov = __shfl_xor(bv, off);
                    int oi = __shfl_xor(bi, off);
                    if (argless(ov, oi, bv, bi)) { bv = ov; bi = oi; }
                }
                int ks = bi;
                int owner = ks & 63, rkk = ks >> 6;
                bool mine = (lane == owner);
                int jg = j0 + jl;
                float z2 = szn2[jl];
                float gnext = havenext ? sgram[jl * 65 + jl + 1] : 0.f;
                float dcsel = 0.f;
                int oldc = 0;
#pragma unroll
                for (int r = 0; r < 8; ++r) {
                    if (r == rkk) { dcsel = d8[r]; oldc = cntg[r]; }
                }
                if (mine) {
                    upd[jg] = ks;
                    rankw[jg] = oldc;
                    int ct = scnt[ks];
                    if (ct == 0) { int n = *snrows; srows[n] = ks; srowidx[ks] = n; *snrows = n + 1; }
                    stwin[jl] = ks;
                    strank[jl] = ct;
                    scnt[ks] = ct + 1;
                }
#pragma unroll
                for (int r = 0; r < 8; ++r) {
                    bool sel = mine && (r == rkk);
                    if (sel) {
                        pn2r[r] = MU * MU * pn2r[r] + 2.f * MU * OMU * dcsel + OMU * OMU * z2;
                        cntg[r] = cntg[r] + 1;
                        pv[r] = MU * pv[r] + OMU * gnext;
                    }
                }
                // row update for remaining in-tile columns
                int x = jl + 1 + lane;
                if (x < tlen) {
                    int a = ks * 65 + x;
                    sdot[a] = MU * sdot[a] + OMU * sgram[jl * 65 + x];
                }
#pragma unroll
                for (int r = 0; r < 8; ++r) d8[r] = pv[r];
            }
            // post-scan bookkeeping for phase U
            if (lane < tlen) {
                int row = stwin[lane];
                int m = scnt[row];
                int e = m - 1 - strank[lane];
                float w = OMU;
                for (int q = 0; q < e; ++q) w *= MU;
                stepw[lane] = w;
            }
            if (lane == 0) {
                int n = *snrows;
                int acc = 0;
                for (int i = 0; i < n; ++i) {
                    srowstart[i] = acc;
                    int m = scnt[srows[i]];
                    float s = 1.f;
                    for (int q = 0; q < m; ++q) s *= MU;
                    srow_scale[i] = s;
                    acc += m;
                }
                srowstart[n] = acc;
            }
            if (lane < tlen) {
                int rowix = srowidx[stwin[lane]];
                sorder[srowstart[rowix] + strank[lane]] = lane;
            }
        }
        __syncthreads();

        // ---- phase U: grouped update of remaining global Dot columns ----
        {
            int nrows = *snrows;
            int tile_end = j0 + tlen;
            int rem = ng - tile_end;
            if (nrows > 0 && rem > 0) {
                int nchunks = (rem + 255) / 256;
                int total = nrows * nchunks;
                for (int item = wave; item < total; item += 8) {
                    int rowix = item % nrows;
                    int chunk = item / nrows;
                    int row = srows[rowix];
                    float scale = srow_scale[rowix];
                    int qs = srowstart[rowix], qe = srowstart[rowix + 1];
                    int xb = tile_end + chunk * 256 + lane * 4;
                    if (xb >= ng) continue;
                    float* dp = Dot + (size_t)row * NGMAX + xb;
                    if (xb + 4 <= ng) {
                        float4 a = *(const float4*)dp;
                        a.x *= scale; a.y *= scale; a.z *= scale; a.w *= scale;
                        for (int q = qs; q < qe; ++q) {
                            int r = sorder[q];
                            float w = stepw[r];
                            const float4 gv = *(const float4*)(Gram + (size_t)(j0 + r) * NGMAX + xb);
                            a.x += w * gv.x; a.y += w * gv.y; a.z += w * gv.z; a.w += w * gv.w;
                        }
                        *(float4*)dp = a;
                    } else {
                        for (int x = xb; x < ng; ++x) {
                            float a = Dot[(size_t)row * NGMAX + x] * scale;
                            for (int q = qs; q < qe; ++q) {
                                int r = sorder[q];
                                a += stepw[r] * Gram[(size_t)(j0 + r) * NGMAX + x];
                            }
                            Dot[(size_t)row * NGMAX + x] = a;
                        }
                    }
                }
            }
        }
        __threadfence();
        __syncthreads();
    }

    if (wave == 0) {
#pragma unroll
        for (int r = 0; r < 8; ++r) cnt_out[r * 64 + lane] = cntg[r];
    }
}

// -------- materialize final prototypes (block per prototype) --------
__global__ void k_mat(const float* __restrict__ Z, const float* __restrict__ P0,
                      const int* __restrict__ gsteps, const int* __restrict__ scal,
                      const int* __restrict__ upd, const int* __restrict__ rankw,
                      const int* __restrict__ cnt, float* __restrict__ Pn) {
    int k = blockIdx.x;
    int tid = threadIdx.x;
    int ng = scal[0];
    int c = cnt[k];
    float bw = powf(MU, (float)c);
    const float4* p0r = (const float4*)(P0 + (size_t)k * D_F);
    float4 a0 = p0r[tid], a1 = p0r[tid + 256];
    a0.x *= bw; a0.y *= bw; a0.z *= bw; a0.w *= bw;
    a1.x *= bw; a1.y *= bw; a1.z *= bw; a1.w *= bw;
    for (int j = 0; j < ng; ++j) {
        if (upd[j] == k) {
            float wgt = OMU * powf(MU, (float)(c - 1 - rankw[j]));
            const float4* zr = (const float4*)(Z + (size_t)gsteps[j] * D_F);
            float4 z0 = zr[tid], z1 = zr[tid + 256];
            a0.x += wgt * z0.x; a0.y += wgt * z0.y; a0.z += wgt * z0.z; a0.w += wgt * z0.w;
            a1.x += wgt * z1.x; a1.y += wgt * z1.y; a1.z += wgt * z1.z; a1.w += wgt * z1.w;
        }
    }
    float4* pnr = (float4*)(Pn + (size_t)k * D_F);
    pnr[tid] = a0;
    pnr[tid + 256] = a1;
}

// -------- top-3 nearest + pull-loss row sums (wave per row) --------
__global__ void k_top3(const float* __restrict__ Dotf, const float* __restrict__ pn2f,
                       const float* __restrict__ Z, const float* __restrict__ Pn,
                       float* __restrict__ rowsum) {
    int row = blockIdx.x * 4 + (threadIdx.x >> 6);
    int lane = threadIdx.x & 63;
    float bv0 = FLTMAX, bv1 = FLTMAX, bv2 = FLTMAX;
    int bi0 = IMAX, bi1 = IMAX, bi2 = IMAX;
    for (int t = 0; t < 8; ++t) {
        int k = lane + 64 * t;
        float v = pn2f[k] - 2.f * Dotf[(size_t)row * K_P + k];
        if (argless(v, k, bv0, bi0)) {
            bv2 = bv1; bi2 = bi1; bv1 = bv0; bi1 = bi0; bv0 = v; bi0 = k;
        } else if (argless(v, k, bv1, bi1)) {
            bv2 = bv1; bi2 = bi1; bv1 = v; bi1 = k;
        } else if (argless(v, k, bv2, bi2)) {
            bv2 = v; bi2 = k;
        }
    }
    for (int off = 32; off; off >>= 1) {
        float a0 = bv0, a1 = bv1, a2 = bv2;
        int x0 = bi0, x1 = bi1, x2 = bi2;
        float b0 = __shfl_xor(bv0, off), b1 = __shfl_xor(bv1, off), b2 = __shfl_xor(bv2, off);
        int y0 = __shfl_xor(bi0, off), y1 = __shfl_xor(bi1, off), y2 = __shfl_xor(bi2, off);
        float nv[3]; int ni[3];
#pragma unroll
        for (int s = 0; s < 3; ++s) {
            bool ta = argless(a0, x0, b0, y0);
            nv[s] = ta ? a0 : b0;
            ni[s] = ta ? x0 : y0;
            if (ta) { a0 = a1; x0 = x1; a1 = a2; x1 = x2; a2 = FLTMAX; x2 = IMAX; }
            else    { b0 = b1; y0 = y1; b1 = b2; y1 = y2; b2 = FLTMAX; y2 = IMAX; }
        }
        bv0 = nv[0]; bv1 = nv[1]; bv2 = nv[2];
        bi0 = ni[0]; bi1 = ni[1]; bi2 = ni[2];
    }
    const float* pa = Pn + (size_t)bi0 * D_F;
    const float* pb = Pn + (size_t)bi1 * D_F;
    const float* pc = Pn + (size_t)bi2 * D_F;
    const float* zr = Z + (size_t)row * D_F;
    const float third = 1.f / 3.f;
    float acc = 0.f;
    for (int d0 = lane * 4; d0 < D_F; d0 += 256) {
        float4 z = *(const float4*)(zr + d0);
        float4 A = *(const float4*)(pa + d0);
        float4 Bv = *(const float4*)(pb + d0);
        float4 C = *(const float4*)(pc + d0);
        float m, df;
        m = (A.x + Bv.x + C.x) * third; df = z.x - m; acc += df * df;
        m = (A.y + Bv.y + C.y) * third; df = z.y - m; acc += df * df;
        m = (A.z + Bv.z + C.z) * third; df = z.z - m; acc += df * df;
        m = (A.w + Bv.w + C.w) * third; df = z.w - m; acc += df * df;
    }
    for (int off = 32; off; off >>= 1) acc += __shfl_xor(acc, off);
    if (lane == 0) rowsum[row] = acc;
}

// -------- push-loss row values (wave per row) --------
__global__ void k_push(const float* __restrict__ Z, const float* __restrict__ m_a_used,
                       const float* __restrict__ zn2, const float* __restrict__ scal_f,
                       float* __restrict__ rowpush) {
    int row = blockIdx.x * 4 + (threadIdx.x >> 6);
    int lane = threadIdx.x & 63;
    const float* zr = Z + (size_t)row * D_F;
    float acc = 0.f;
    for (int d0 = lane * 4; d0 < D_F; d0 += 256) {
        float4 z = *(const float4*)(zr + d0);
        float4 m = *(const float4*)(m_a_used + d0);
        acc += z.x * m.x + z.y * m.y + z.z * m.z + z.w * m.w;
    }
    for (int off = 32; off; off >>= 1) acc += __shfl_xor(acc, off);
    if (lane == 0) {
        float d2 = zn2[row] - 2.f * acc + scal_f[0];
        float dist = sqrtf(fmaxf(d2, 0.f));
        rowpush[row] = fmaxf(1.f - dist, 0.f);
    }
}

// -------- final combine --------
__global__ void k_final(const float* __restrict__ rowsum, const float* __restrict__ rowpush,
                        const int* __restrict__ scal, float* __restrict__ out) {
    __shared__ float red[1024];
    int tid = threadIdx.x;
    float s = 0.f;
    for (int i = tid; i < B_N; i += 1024) s += rowsum[i];
    red[tid] = s;
    __syncthreads();
    for (int off = 512; off; off >>= 1) {
        if (tid < off) red[tid] += red[tid + off];
        __syncthreads();
    }
    float pull = red[0] / ((float)B_N * (float)D_F);
    __syncthreads();
    float p = 0.f;
    for (int i = tid; i < B_N; i += 1024) p += rowpush[i];
    red[tid] = p;
    __syncthreads();
    for (int off = 512; off; off >>= 1) {
        if (tid < off) red[tid] += red[tid + off];
        __syncthreads();
    }
    if (tid == 0) {
        float lpush = (scal[1] > 0) ? (red[0] / (float)B_N) : 0.f;
        out[0] = pull + 0.5f * lpush;
    }
}

extern "C" void kernel_launch(void* const* d_in, const int* in_sizes, int n_in,
                              void* d_out, int out_size, void* d_ws, size_t ws_size,
                              hipStream_t stream) {
    const float* Z = (const float*)d_in[0];
    const int* g = (const int*)d_in[1];
    const float* P0 = (const float*)d_in[2];
    const float* ma_in = (const float*)d_in[4];
    float* out = (float*)d_out;

    float* ws = (float*)d_ws;
    float* Gram = ws;
    float* Dotf = ws;
    float* Dot = ws + (size_t)NGMAX * NGMAX;
    float* Pn = Dot + (size_t)K_P * NGMAX;
    float* zn2 = Pn + (size_t)K_P * D_F;
    float* pn2_0 = zn2 + B_N;
    float* pn2f = pn2_0 + K_P;
    float* anom_part = pn2f + K_P;
    float* m_a_used = anom_part + 32 * D_F;
    float* rowsum = m_a_used + D_F;
    float* rowpush = rowsum + B_N;
    float* scal_f = rowpush + B_N;
    int* gsteps = (int*)(scal_f + 16);
    int* upd = gsteps + B_N;
    int* rankw = upd + B_N;
    int* cnt = rankw + B_N;
    int* scal = cnt + K_P;

    hipFuncSetAttribute((const void*)k_scan_tiled,
                        hipFuncAttributeMaxDynamicSharedMemorySize, SMEM_BYTES);

    k_prep<<<1, 1024, 0, stream>>>(g, gsteps, scal);
    k_rownorm<<<(B_N + 3) / 4, 256, 0, stream>>>(Z, zn2, B_N);
    k_rownorm<<<(K_P + 3) / 4, 256, 0, stream>>>(P0, pn2_0, K_P);
    k_colsum<<<dim3(D_F / 256, 32), 256, 0, stream>>>(Z, g, anom_part);
    k_fin_ma<<<1, 1024, 0, stream>>>(anom_part, ma_in, scal, m_a_used, scal_f);
    k_gemm<0><<<dim3(NGMAX / 64, (NGMAX + K_P) / 64), 256, 0, stream>>>(
        Z, P0, Pn, gsteps, scal, Gram, Dot, Dotf);
    k_scan_tiled<<<1, 512, SMEM_BYTES, stream>>>(Gram, Dot, pn2_0, zn2, gsteps, scal,
                                                 upd, rankw, cnt);
    k_mat<<<K_P, 256, 0, stream>>>(Z, P0, gsteps, scal, upd, rankw, cnt, Pn);
    k_rownorm<<<(K_P + 3) / 4, 256, 0, stream>>>(Pn, pn2f, K_P);
    k_gemm<1><<<dim3(K_P / 64, B_N / 64), 256, 0, stream>>>(
        Z, P0, Pn, gsteps, scal, Gram, Dot, Dotf);
    k_top3<<<B_N / 4, 256, 0, stream>>>(Dotf, pn2f, Z, Pn, rowsum);
    k_push<<<B_N / 4, 256, 0, stream>>>(Z, m_a_used, zn2, scal_f, rowpush);
    k_final<<<1, 1024, 0, stream>>>(rowsum, rowpush, scal, out);
}

// Round 3
// 3326.237 us; speedup vs baseline: 1.4177x; 1.3563x over previous
//
#include <hip/hip_runtime.h>
#include <math.h>

#define B_N 4096
#define D_F 2048
#define K_P 512
#define NGMAX 4096
#define MU 0.9f
#define OMU (1.0f - MU)
#define FLTMAX 3.402823466e+38f
#define IMAX 0x7FFFFFFF
#define TILE 64
#define SDPITCH 513

// LDS carve (floats/ints)
#define SMEM_FLOATS (64 * SDPITCH + 64 * 65 + 64 + 64 + 64)
#define SMEM_INTS (64 * 4 + 512 + 1)
#define SMEM_BYTES ((SMEM_FLOATS + SMEM_INTS) * 4)

__device__ __forceinline__ bool argless(float v1, int i1, float v2, int i2) {
    return (v1 < v2) || (v1 == v2 && i1 < i2);
}

// DPP min-reduce helpers: after the 6-step sequence lane 63 holds the wave min.
template <int CTRL>
__device__ __forceinline__ float dppmin_f(float v) {
    int t = __builtin_amdgcn_update_dpp(__float_as_int(v), __float_as_int(v), CTRL, 0xf, 0xf, false);
    return fminf(v, __int_as_float(t));
}
template <int CTRL>
__device__ __forceinline__ int dppmin_i(int v) {
    int t = __builtin_amdgcn_update_dpp(v, v, CTRL, 0xf, 0xf, false);
    return min(v, t);
}
__device__ __forceinline__ float wave_min_f(float v) {
    v = dppmin_f<0x111>(v);  // row_shr:1
    v = dppmin_f<0x112>(v);  // row_shr:2
    v = dppmin_f<0x114>(v);  // row_shr:4
    v = dppmin_f<0x118>(v);  // row_shr:8
    v = dppmin_f<0x142>(v);  // row_bcast:15
    v = dppmin_f<0x143>(v);  // row_bcast:31
    return __int_as_float(__builtin_amdgcn_readlane(__float_as_int(v), 63));
}
__device__ __forceinline__ int wave_min_i(int v) {
    v = dppmin_i<0x111>(v);
    v = dppmin_i<0x112>(v);
    v = dppmin_i<0x114>(v);
    v = dppmin_i<0x118>(v);
    v = dppmin_i<0x142>(v);
    v = dppmin_i<0x143>(v);
    return __builtin_amdgcn_readlane(v, 63);
}

// -------- prep: compact gated indices, counts --------
__global__ void k_prep(const int* __restrict__ g, int* __restrict__ gsteps,
                       int* __restrict__ scal) {
    __shared__ int s[1024];
    __shared__ int base;
    int tid = threadIdx.x;
    if (tid == 0) base = 0;
    __syncthreads();
    for (int c = 0; c < 4; ++c) {
        int i = c * 1024 + tid;
        int gi = (g[i] != 0) ? 1 : 0;
        s[tid] = gi;
        __syncthreads();
        for (int off = 1; off < 1024; off <<= 1) {
            int v = (tid >= off) ? s[tid - off] : 0;
            __syncthreads();
            s[tid] += v;
            __syncthreads();
        }
        int pos = base + s[tid] - 1;
        if (gi) gsteps[pos] = i;
        __syncthreads();
        if (tid == 1023) base += s[1023];
        __syncthreads();
    }
    if (tid == 0) { scal[0] = base; scal[1] = B_N - base; }
}

// -------- row squared norms (wave per row) --------
__global__ void k_rownorm(const float* __restrict__ src, float* __restrict__ dst, int nrows) {
    int row = blockIdx.x * 4 + (threadIdx.x >> 6);
    int lane = threadIdx.x & 63;
    if (row >= nrows) return;
    const float* p = src + (size_t)row * D_F;
    float acc = 0.f;
    for (int d0 = lane * 4; d0 < D_F; d0 += 256) {
        float4 v = *(const float4*)(p + d0);
        acc += v.x * v.x + v.y * v.y + v.z * v.z + v.w * v.w;
    }
    for (int off = 32; off; off >>= 1) acc += __shfl_xor(acc, off);
    if (lane == 0) dst[row] = acc;
}

// -------- anomaly column sums (partials) --------
__global__ void k_colsum(const float* __restrict__ Z, const int* __restrict__ g,
                         float* __restrict__ anom_part) {
    int d = blockIdx.x * 256 + threadIdx.x;
    int rc = blockIdx.y;
    float acc = 0.f;
    int r0 = rc * 128;
    for (int r = r0; r < r0 + 128; ++r) {
        if (g[r] == 0) acc += Z[(size_t)r * D_F + d];
    }
    anom_part[(size_t)rc * D_F + d] = acc;
}

// -------- finalize m_a --------
__global__ void k_fin_ma(const float* __restrict__ anom_part, const float* __restrict__ ma_in,
                         const int* __restrict__ scal, float* __restrict__ m_a_used,
                         float* __restrict__ scal_f) {
    __shared__ float red[1024];
    int tid = threadIdx.x;
    int na = scal[1];
    float m2 = 0.f;
    for (int dd = tid; dd < D_F; dd += 1024) {
        float s = 0.f;
        for (int c = 0; c < 32; ++c) s += anom_part[(size_t)c * D_F + dd];
        float v = (na > 0) ? (s / (float)na) : ma_in[dd];
        m_a_used[dd] = v;
        m2 += v * v;
    }
    red[tid] = m2;
    __syncthreads();
    for (int off = 512; off; off >>= 1) {
        if (tid < off) red[tid] += red[tid + off];
        __syncthreads();
    }
    if (tid == 0) scal_f[0] = red[0];
}

// -------- GEMM (NT: C = A * B^T), 64x64 tile, BK=16, 256 thr, 4x4 micro --------
template <int MODE>
__global__ void k_gemm(const float* __restrict__ Z, const float* __restrict__ P0,
                       const float* __restrict__ Pn, const int* __restrict__ gsteps,
                       const int* __restrict__ scal, float* __restrict__ Gram,
                       float* __restrict__ Dot, float* __restrict__ Dotf) {
    int ng = scal[0];
    int M = (MODE == 0) ? (ng + K_P) : B_N;
    int N = (MODE == 0) ? ng : K_P;
    int mb = blockIdx.y * 64, nb = blockIdx.x * 64;
    if (mb >= M || nb >= N) return;
    // Gram is symmetric; only its upper triangle (col > row) is consumed.
    if (MODE == 0 && (mb + 64 <= ng) && (nb + 64 <= mb)) return;

    __shared__ float As[16][68];
    __shared__ float Bs[16][68];
    __shared__ const float* rowA[64];
    __shared__ const float* rowB[64];

    int tid = threadIdx.x;
    if (tid < 64) {
        int gm = mb + tid;
        const float* pa = nullptr;
        if (MODE == 0) {
            if (gm < ng) pa = Z + (size_t)gsteps[gm] * D_F;
            else if (gm < ng + K_P) pa = P0 + (size_t)(gm - ng) * D_F;
        } else {
            if (gm < B_N) pa = Z + (size_t)gm * D_F;
        }
        rowA[tid] = pa;
    } else if (tid < 128) {
        int t = tid - 64;
        int gn = nb + t;
        const float* pb = nullptr;
        if (MODE == 0) { if (gn < ng) pb = Z + (size_t)gsteps[gn] * D_F; }
        else { if (gn < K_P) pb = Pn + (size_t)gn * D_F; }
        rowB[t] = pb;
    }
    __syncthreads();

    int r = tid & 63, kq = tid >> 6;
    int tm = tid >> 4, tn = tid & 15;
    const float* pa = rowA[r];
    const float* pb = rowB[r];

    float acc[4][4] = {};
    for (int k0 = 0; k0 < D_F; k0 += 16) {
        float4 av = pa ? *(const float4*)(pa + k0 + kq * 4) : make_float4(0.f, 0.f, 0.f, 0.f);
        float4 bv = pb ? *(const float4*)(pb + k0 + kq * 4) : make_float4(0.f, 0.f, 0.f, 0.f);
        __syncthreads();
        As[kq * 4 + 0][r] = av.x; As[kq * 4 + 1][r] = av.y;
        As[kq * 4 + 2][r] = av.z; As[kq * 4 + 3][r] = av.w;
        Bs[kq * 4 + 0][r] = bv.x; Bs[kq * 4 + 1][r] = bv.y;
        Bs[kq * 4 + 2][r] = bv.z; Bs[kq * 4 + 3][r] = bv.w;
        __syncthreads();
#pragma unroll
        for (int kk = 0; kk < 16; ++kk) {
            float4 a = *(const float4*)&As[kk][tm * 4];
            float4 b = *(const float4*)&Bs[kk][tn * 4];
            float aa[4] = {a.x, a.y, a.z, a.w};
            float bb[4] = {b.x, b.y, b.z, b.w};
#pragma unroll
            for (int i = 0; i < 4; ++i)
#pragma unroll
                for (int j = 0; j < 4; ++j) acc[i][j] += aa[i] * bb[j];
        }
    }

#pragma unroll
    for (int i = 0; i < 4; ++i) {
        int gm = mb + tm * 4 + i;
        if (gm >= M) continue;
        float* crow;
        if (MODE == 0)
            crow = (gm < ng) ? (Gram + (size_t)gm * NGMAX) : (Dot + (size_t)(gm - ng) * NGMAX);
        else
            crow = Dotf + (size_t)gm * K_P;
#pragma unroll
        for (int j = 0; j < 4; ++j) {
            int gn = nb + tn * 4 + j;
            if (gn < N) crow[gn] = acc[i][j];
        }
    }
}

// -------- tiled sequential scan, DPP-reduction hot loop --------
__global__ __launch_bounds__(512, 1)
void k_scan_tiled(const float* __restrict__ Gram, float* __restrict__ Dot,
                  const float* __restrict__ pn2_0, const float* __restrict__ zn2,
                  const int* __restrict__ gsteps, const int* __restrict__ scal,
                  int* __restrict__ upd, int* __restrict__ rankw, int* __restrict__ cnt_out) {
    extern __shared__ char smem_raw[];
    float* sdot = (float*)smem_raw;             // [64][SDPITCH] transposed: sdot[x][k]
    float* sgram = sdot + 64 * SDPITCH;         // [64][65]
    float* szn2 = sgram + 64 * 65;              // [64]
    float* stepw = szn2 + 64;                   // [64] per-step weight
    float* sscale = stepw + 64;                 // [64] per-row mu^m
    int* srows = (int*)(sscale + 64);           // [64]
    int* sqs = srows + 64;                      // [64]
    int* sqe = sqs + 64;                        // [64]
    int* sorder = sqe + 64;                     // [64]
    int* rowcnt = sorder + 64;                  // [512] global win counts
    int* snrows = rowcnt + 512;                 // [1]

    int tid = threadIdx.x;
    int lane = tid & 63;
    int wave = tid >> 6;
    int ng = scal[0];

    rowcnt[tid] = 0;

    // wave-0 lane-private state: lane owns prototypes k = r*64 + lane
    float pn2r[8];
    if (wave == 0) {
#pragma unroll
        for (int r = 0; r < 8; ++r) pn2r[r] = pn2_0[r * 64 + lane];
    }

    int ntiles = (ng + TILE - 1) / TILE;
    for (int T = 0; T < ntiles; ++T) {
        int j0 = T * TILE;
        int tlen = min(TILE, ng - j0);

        // ---- phase L: load dot tile (transposed) + gram block ----
        {
            const float* src = Dot + (size_t)tid * NGMAX + j0;
#pragma unroll
            for (int x = 0; x < 64; x += 4) {
                float4 v = *(const float4*)(src + x);
                sdot[(x + 0) * SDPITCH + tid] = v.x;
                sdot[(x + 1) * SDPITCH + tid] = v.y;
                sdot[(x + 2) * SDPITCH + tid] = v.z;
                sdot[(x + 3) * SDPITCH + tid] = v.w;
            }
        }
        {
            int t = tid >> 3, xo = (tid & 7) * 8;
            const float* src = Gram + (size_t)(j0 + t) * NGMAX + j0 + xo;
            float4 a = *(const float4*)(src);
            float4 b = *(const float4*)(src + 4);
            float* dst = sgram + t * 65 + xo;
            dst[0] = a.x; dst[1] = a.y; dst[2] = a.z; dst[3] = a.w;
            dst[4] = b.x; dst[5] = b.y; dst[6] = b.z; dst[7] = b.w;
        }
        if (tid < TILE) {
            if (tid < tlen) szn2[tid] = zn2[gsteps[j0 + tid]];
            else szn2[tid] = 0.f;
        }
        __syncthreads();

        // ---- phase S (wave 0 only) ----
        if (wave == 0) {
            float d8[8];
#pragma unroll
            for (int r = 0; r < 8; ++r) d8[r] = sdot[r * 64 + lane];  // col 0
            float z2c = szn2[0];
            float gnc = sgram[1];  // G[0][1]
            int stw_reg = 0;

            for (int jl = 0; jl < tlen; ++jl) {
                // prefetch next column + scalars (addresses independent of argmin)
                float pv[8];
                float nz2 = 0.f, ngn = 0.f;
                const bool hn = (jl + 1 < tlen);
                if (hn) {
                    const float* cb = sdot + (jl + 1) * SDPITCH;
#pragma unroll
                    for (int r = 0; r < 8; ++r) pv[r] = cb[r * 64 + lane];
                    nz2 = szn2[jl + 1];
                    ngn = sgram[(jl + 1) * 65 + (jl + 2)];
                } else {
#pragma unroll
                    for (int r = 0; r < 8; ++r) pv[r] = 0.f;
                }

                // local argmin over lane's 8 prototypes (first-min, ascending r)
                float lm = pn2r[0] - 2.f * d8[0];
                int lr = 0;
#pragma unroll
                for (int r = 1; r < 8; ++r) {
                    float v = pn2r[r] - 2.f * d8[r];
                    if (v < lm) { lm = v; lr = r; }
                }

                // wave min value (DPP), then exact smallest index among ties
                float m = wave_min_f(lm);
                int key = (lm == m) ? (lr * 64 + lane) : IMAX;
                int ks = wave_min_i(key);
                int wlane = ks & 63, wr = ks >> 6;

                if (lane == jl) stw_reg = ks;  // record winner in register (lane jl)

                bool mine = (lane == wlane);
                float z2 = z2c, gn = gnc;
#pragma unroll
                for (int r = 0; r < 8; ++r) {
                    if (mine && r == wr) {
                        pn2r[r] = MU * MU * pn2r[r] + 2.f * MU * OMU * d8[r] + OMU * OMU * z2;
                        pv[r] = MU * pv[r] + OMU * gn;
                    }
                }

                // winner-row update for future in-tile columns (col jl+1 handled via pv fixup)
                int x = jl + 2 + lane;
                if (x < tlen) {
                    float* dp = sdot + x * SDPITCH + ks;
                    *dp = MU * *dp + OMU * sgram[jl * 65 + x];
                }

#pragma unroll
                for (int r = 0; r < 8; ++r) d8[r] = pv[r];
                z2c = nz2; gnc = ngn;
            }

            // ---- post-pass: per-tile bookkeeping (once, not per-step) ----
            int wj = stw_reg;
            bool valid = (lane < tlen);
            int fp = 127, rank = 0, mrow = 0;
            for (int i = 0; i < tlen; ++i) {
                int wi = __builtin_amdgcn_readlane(wj, i);
                bool match = valid && (wi == wj);
                if (match) {
                    mrow++;
                    if (i < lane) rank++;
                    if (i < fp) fp = i;
                }
            }
            bool first = valid && (rank == 0);
            unsigned long long fmask = __ballot(first);
            int pos = rank;
            for (int i = 0; i < tlen; ++i) {
                int fpi = __builtin_amdgcn_readlane(fp, i);
                if (valid && fpi < fp) pos++;
            }
            if (valid) {
                int jg = j0 + lane;
                upd[jg] = wj;
                rankw[jg] = rowcnt[wj] + rank;  // read before firsts update rowcnt
                sorder[pos] = lane;
                stepw[lane] = OMU * exp2f((float)(mrow - 1 - rank) * -0.15200309344504997f);
            }
            if (first) {
                int rowix = __popcll(fmask & ((1ULL << lane) - 1));
                srows[rowix] = wj;
                sqs[rowix] = pos;
                sqe[rowix] = pos + mrow;
                sscale[rowix] = exp2f((float)mrow * -0.15200309344504997f);
                rowcnt[wj] += mrow;
            }
            if (lane == 0) *snrows = __popcll(fmask);
        }
        __syncthreads();

        // ---- phase U: grouped update of remaining global Dot columns ----
        {
            int nrows = *snrows;
            int tile_end = j0 + tlen;
            int rem = ng - tile_end;
            if (nrows > 0 && rem > 0) {
                int nchunks = (rem + 255) / 256;
                int total = nrows * nchunks;
                for (int item = wave; item < total; item += 8) {
                    int rowix = item % nrows;
                    int chunk = item / nrows;
                    int row = srows[rowix];
                    float scale = sscale[rowix];
                    int qs = sqs[rowix], qe = sqe[rowix];
                    int xb = tile_end + chunk * 256 + lane * 4;
                    if (xb >= ng) continue;
                    float* dp = Dot + (size_t)row * NGMAX + xb;
                    if (xb + 4 <= ng) {
                        float4 a = *(const float4*)dp;
                        a.x *= scale; a.y *= scale; a.z *= scale; a.w *= scale;
                        for (int q = qs; q < qe; ++q) {
                            int r = sorder[q];
                            float w = stepw[r];
                            const float4 gv = *(const float4*)(Gram + (size_t)(j0 + r) * NGMAX + xb);
                            a.x += w * gv.x; a.y += w * gv.y; a.z += w * gv.z; a.w += w * gv.w;
                        }
                        *(float4*)dp = a;
                    } else {
                        for (int x = xb; x < ng; ++x) {
                            float a = Dot[(size_t)row * NGMAX + x] * scale;
                            for (int q = qs; q < qe; ++q) {
                                int r = sorder[q];
                                a += stepw[r] * Gram[(size_t)(j0 + r) * NGMAX + x];
                            }
                            Dot[(size_t)row * NGMAX + x] = a;
                        }
                    }
                }
            }
        }
        __syncthreads();
    }

    cnt_out[tid] = rowcnt[tid];
}

// -------- materialize final prototypes (block per prototype) --------
__global__ void k_mat(const float* __restrict__ Z, const float* __restrict__ P0,
                      const int* __restrict__ gsteps, const int* __restrict__ scal,
                      const int* __restrict__ upd, const int* __restrict__ rankw,
                      const int* __restrict__ cnt, float* __restrict__ Pn) {
    int k = blockIdx.x;
    int tid = threadIdx.x;
    int ng = scal[0];
    int c = cnt[k];
    float bw = powf(MU, (float)c);
    const float4* p0r = (const float4*)(P0 + (size_t)k * D_F);
    float4 a0 = p0r[tid], a1 = p0r[tid + 256];
    a0.x *= bw; a0.y *= bw; a0.z *= bw; a0.w *= bw;
    a1.x *= bw; a1.y *= bw; a1.z *= bw; a1.w *= bw;
    for (int j = 0; j < ng; ++j) {
        if (upd[j] == k) {
            float wgt = OMU * powf(MU, (float)(c - 1 - rankw[j]));
            const float4* zr = (const float4*)(Z + (size_t)gsteps[j] * D_F);
            float4 z0 = zr[tid], z1 = zr[tid + 256];
            a0.x += wgt * z0.x; a0.y += wgt * z0.y; a0.z += wgt * z0.z; a0.w += wgt * z0.w;
            a1.x += wgt * z1.x; a1.y += wgt * z1.y; a1.z += wgt * z1.z; a1.w += wgt * z1.w;
        }
    }
    float4* pnr = (float4*)(Pn + (size_t)k * D_F);
    pnr[tid] = a0;
    pnr[tid + 256] = a1;
}

// -------- top-3 nearest + pull-loss row sums (wave per row) --------
__global__ void k_top3(const float* __restrict__ Dotf, const float* __restrict__ pn2f,
                       const float* __restrict__ Z, const float* __restrict__ Pn,
                       float* __restrict__ rowsum) {
    int row = blockIdx.x * 4 + (threadIdx.x >> 6);
    int lane = threadIdx.x & 63;
    float bv0 = FLTMAX, bv1 = FLTMAX, bv2 = FLTMAX;
    int bi0 = IMAX, bi1 = IMAX, bi2 = IMAX;
    for (int t = 0; t < 8; ++t) {
        int k = lane + 64 * t;
        float v = pn2f[k] - 2.f * Dotf[(size_t)row * K_P + k];
        if (argless(v, k, bv0, bi0)) {
            bv2 = bv1; bi2 = bi1; bv1 = bv0; bi1 = bi0; bv0 = v; bi0 = k;
        } else if (argless(v, k, bv1, bi1)) {
            bv2 = bv1; bi2 = bi1; bv1 = v; bi1 = k;
        } else if (argless(v, k, bv2, bi2)) {
            bv2 = v; bi2 = k;
        }
    }
    for (int off = 32; off; off >>= 1) {
        float a0 = bv0, a1 = bv1, a2 = bv2;
        int x0 = bi0, x1 = bi1, x2 = bi2;
        float b0 = __shfl_xor(bv0, off), b1 = __shfl_xor(bv1, off), b2 = __shfl_xor(bv2, off);
        int y0 = __shfl_xor(bi0, off), y1 = __shfl_xor(bi1, off), y2 = __shfl_xor(bi2, off);
        float nv[3]; int ni[3];
#pragma unroll
        for (int s = 0; s < 3; ++s) {
            bool ta = argless(a0, x0, b0, y0);
            nv[s] = ta ? a0 : b0;
            ni[s] = ta ? x0 : y0;
            if (ta) { a0 = a1; x0 = x1; a1 = a2; x1 = x2; a2 = FLTMAX; x2 = IMAX; }
            else    { b0 = b1; y0 = y1; b1 = b2; y1 = y2; b2 = FLTMAX; y2 = IMAX; }
        }
        bv0 = nv[0]; bv1 = nv[1]; bv2 = nv[2];
        bi0 = ni[0]; bi1 = ni[1]; bi2 = ni[2];
    }
    const float* pa = Pn + (size_t)bi0 * D_F;
    const float* pb = Pn + (size_t)bi1 * D_F;
    const float* pc = Pn + (size_t)bi2 * D_F;
    const float* zr = Z + (size_t)row * D_F;
    const float third = 1.f / 3.f;
    float acc = 0.f;
    for (int d0 = lane * 4; d0 < D_F; d0 += 256) {
        float4 z = *(const float4*)(zr + d0);
        float4 A = *(const float4*)(pa + d0);
        float4 Bv = *(const float4*)(pb + d0);
        float4 C = *(const float4*)(pc + d0);
        float m, df;
        m = (A.x + Bv.x + C.x) * third; df = z.x - m; acc += df * df;
        m = (A.y + Bv.y + C.y) * third; df = z.y - m; acc += df * df;
        m = (A.z + Bv.z + C.z) * third; df = z.z - m; acc += df * df;
        m = (A.w + Bv.w + C.w) * third; df = z.w - m; acc += df * df;
    }
    for (int off = 32; off; off >>= 1) acc += __shfl_xor(acc, off);
    if (lane == 0) rowsum[row] = acc;
}

// -------- push-loss row values (wave per row) --------
__global__ void k_push(const float* __restrict__ Z, const float* __restrict__ m_a_used,
                       const float* __restrict__ zn2, const float* __restrict__ scal_f,
                       float* __restrict__ rowpush) {
    int row = blockIdx.x * 4 + (threadIdx.x >> 6);
    int lane = threadIdx.x & 63;
    const float* zr = Z + (size_t)row * D_F;
    float acc = 0.f;
    for (int d0 = lane * 4; d0 < D_F; d0 += 256) {
        float4 z = *(const float4*)(zr + d0);
        float4 m = *(const float4*)(m_a_used + d0);
        acc += z.x * m.x + z.y * m.y + z.z * m.z + z.w * m.w;
    }
    for (int off = 32; off; off >>= 1) acc += __shfl_xor(acc, off);
    if (lane == 0) {
        float d2 = zn2[row] - 2.f * acc + scal_f[0];
        float dist = sqrtf(fmaxf(d2, 0.f));
        rowpush[row] = fmaxf(1.f - dist, 0.f);
    }
}

// -------- final combine --------
__global__ void k_final(const float* __restrict__ rowsum, const float* __restrict__ rowpush,
                        const int* __restrict__ scal, float* __restrict__ out) {
    __shared__ float red[1024];
    int tid = threadIdx.x;
    float s = 0.f;
    for (int i = tid; i < B_N; i += 1024) s += rowsum[i];
    red[tid] = s;
    __syncthreads();
    for (int off = 512; off; off >>= 1) {
        if (tid < off) red[tid] += red[tid + off];
        __syncthreads();
    }
    float pull = red[0] / ((float)B_N * (float)D_F);
    __syncthreads();
    float p = 0.f;
    for (int i = tid; i < B_N; i += 1024) p += rowpush[i];
    red[tid] = p;
    __syncthreads();
    for (int off = 512; off; off >>= 1) {
        if (tid < off) red[tid] += red[tid + off];
        __syncthreads();
    }
    if (tid == 0) {
        float lpush = (scal[1] > 0) ? (red[0] / (float)B_N) : 0.f;
        out[0] = pull + 0.5f * lpush;
    }
}

extern "C" void kernel_launch(void* const* d_in, const int* in_sizes, int n_in,
                              void* d_out, int out_size, void* d_ws, size_t ws_size,
                              hipStream_t stream) {
    const float* Z = (const float*)d_in[0];
    const int* g = (const int*)d_in[1];
    const float* P0 = (const float*)d_in[2];
    const float* ma_in = (const float*)d_in[4];
    float* out = (float*)d_out;

    float* ws = (float*)d_ws;
    float* Gram = ws;
    float* Dotf = ws;
    float* Dot = ws + (size_t)NGMAX * NGMAX;
    float* Pn = Dot + (size_t)K_P * NGMAX;
    float* zn2 = Pn + (size_t)K_P * D_F;
    float* pn2_0 = zn2 + B_N;
    float* pn2f = pn2_0 + K_P;
    float* anom_part = pn2f + K_P;
    float* m_a_used = anom_part + 32 * D_F;
    float* rowsum = m_a_used + D_F;
    float* rowpush = rowsum + B_N;
    float* scal_f = rowpush + B_N;
    int* gsteps = (int*)(scal_f + 16);
    int* upd = gsteps + B_N;
    int* rankw = upd + B_N;
    int* cnt = rankw + B_N;
    int* scal = cnt + K_P;

    hipFuncSetAttribute((const void*)k_scan_tiled,
                        hipFuncAttributeMaxDynamicSharedMemorySize, SMEM_BYTES);

    k_prep<<<1, 1024, 0, stream>>>(g, gsteps, scal);
    k_rownorm<<<(B_N + 3) / 4, 256, 0, stream>>>(Z, zn2, B_N);
    k_rownorm<<<(K_P + 3) / 4, 256, 0, stream>>>(P0, pn2_0, K_P);
    k_colsum<<<dim3(D_F / 256, 32), 256, 0, stream>>>(Z, g, anom_part);
    k_fin_ma<<<1, 1024, 0, stream>>>(anom_part, ma_in, scal, m_a_used, scal_f);
    k_gemm<0><<<dim3(NGMAX / 64, (NGMAX + K_P) / 64), 256, 0, stream>>>(
        Z, P0, Pn, gsteps, scal, Gram, Dot, Dotf);
    k_scan_tiled<<<1, 512, SMEM_BYTES, stream>>>(Gram, Dot, pn2_0, zn2, gsteps, scal,
                                                 upd, rankw, cnt);
    k_mat<<<K_P, 256, 0, stream>>>(Z, P0, gsteps, scal, upd, rankw, cnt, Pn);
    k_rownorm<<<(K_P + 3) / 4, 256, 0, stream>>>(Pn, pn2f, K_P);
    k_gemm<1><<<dim3(K_P / 64, B_N / 64), 256, 0, stream>>>(
        Z, P0, Pn, gsteps, scal, Gram, Dot, Dotf);
    k_top3<<<B_N / 4, 256, 0, stream>>>(Dotf, pn2f, Z, Pn, rowsum);
    k_push<<<B_N / 4, 256, 0, stream>>>(Z, m_a_used, zn2, scal_f, rowpush);
    k_final<<<1, 1024, 0, stream>>>(rowsum, rowpush, scal, out);
}